// Round 1
// baseline (388.011 us; speedup 1.0000x reference)
//
#include <hip/hip_runtime.h>
#include <hip/hip_bf16.h>

// DiffAlphaSplitModel: VOCAB=64, H=64, HALF=32, B=256, L=2048.
// Key ideas:
//  1) Only 64 distinct tokens -> precompute per-vocab tables for
//     hs, he (unnormalized projections) and ks, ke (normalized keys).
//  2) r = M_L q expands to a backward vector recurrence:
//       u_{L-1} = q;  d_p = k_p . u_p;  r += c_p * d_p * h_p;  u -= c_p * k_p * d_p
//     (s-memory: c=1; e-memory: c=(p+1)/L). O(HALF) per step, no M matrix.

#define L_SEQ 2048
#define NPOS  2047   // L-1 scan positions

// ---------------- Kernel A: per-vocab tables -------------------------------
// grid 64 (one block per vocab id), block 64 threads (== 1 wave)
// tabs layout (floats): [0 .. 4095]  = k tables:  ks[v][j] at (0*64+v)*32+j, ke at (1*64+v)*32+j
//                       [4096..8191] = h tables:  hs / he same layout
__global__ void build_tables(const float* __restrict__ embed,
                             const float* __restrict__ w1, const float* __restrict__ b1,
                             const float* __restrict__ w2, const float* __restrict__ b2,
                             const float* __restrict__ ln_g, const float* __restrict__ ln_b,
                             const float* __restrict__ ws, const float* __restrict__ bs,
                             const float* __restrict__ we, const float* __restrict__ be,
                             float* __restrict__ tabs) {
    const int v = blockIdx.x;
    const int t = threadIdx.x;        // 0..63
    __shared__ float sh_h[64];
    __shared__ float sh_a[128];
    __shared__ float sh_x[64];

    sh_h[t] = embed[v * 64 + t];
    __syncthreads();

    // FF1: (64 -> 128), thread t computes outputs t and t+64
    float acc0 = b1[t], acc1 = b1[t + 64];
    #pragma unroll 8
    for (int k = 0; k < 64; ++k) {
        const float hv = sh_h[k];
        acc0 += hv * w1[k * 128 + t];
        acc1 += hv * w1[k * 128 + t + 64];
    }
    sh_a[t]      = fmaxf(acc0, 0.f);
    sh_a[t + 64] = fmaxf(acc1, 0.f);
    __syncthreads();

    // FF2 (128 -> 64) + residual
    float x = sh_h[t] + b2[t];
    #pragma unroll 8
    for (int k = 0; k < 128; ++k) x += sh_a[k] * w2[k * 64 + t];

    // LayerNorm over 64 (one wave)
    float mu = x;
    for (int m = 1; m <= 32; m <<= 1) mu += __shfl_xor(mu, m);
    mu *= (1.f / 64.f);
    const float dx = x - mu;
    float var = dx * dx;
    for (int m = 1; m <= 32; m <<= 1) var += __shfl_xor(var, m);
    var *= (1.f / 64.f);
    const float hln = dx * rsqrtf(var + 1e-5f) * ln_g[t] + ln_b[t];
    sh_x[t] = hln;
    __syncthreads();

    // projections: lanes 0-31 -> hs (ws,bs), lanes 32-63 -> he (we,be)
    const int j   = t & 31;
    const int mem = t >> 5;
    const float* W  = mem ? we : ws;
    const float* Bv = mem ? be : bs;
    float p = Bv[j];
    #pragma unroll 8
    for (int k = 0; k < 64; ++k) p += sh_x[k] * W[k * 32 + j];

    // L2 norm within each 32-lane half
    float nn = p * p;
    for (int m = 1; m <= 16; m <<= 1) nn += __shfl_xor(nn, m);
    const float kn = p / fmaxf(sqrtf(nn), 1e-12f);

    tabs[(mem * 64 + v) * 32 + j]        = kn;  // normalized key table
    tabs[4096 + (mem * 64 + v) * 32 + j] = p;   // raw projection table
}

// ---------------- Kernel B: backward scan ----------------------------------
// grid 256 (one block per batch), block 64 (lanes 0-31: s-chain, 32-63: e-chain)
__global__ void scan_kernel(const int* __restrict__ seq,
                            const float* __restrict__ tabs,
                            float* __restrict__ rbuf) {
    const int b    = blockIdx.x;
    const int lane = threadIdx.x;
    const int j    = lane & 31;
    const int mem  = lane >> 5;

    __shared__ float ktab[2 * 64 * 32];
    __shared__ float htab[2 * 64 * 32];
    {
        const float4* src = (const float4*)tabs;
        float4* dk = (float4*)ktab;
        float4* dh = (float4*)htab;
        for (int i = lane; i < 1024; i += 64) {
            dk[i] = src[i];
            dh[i] = src[1024 + i];
        }
    }
    __syncthreads();

    const int* srow = seq + b * L_SEQ;
    const float* K = ktab + mem * 2048;
    const float* H = htab + mem * 2048;

    // u initialized with the (normalized) query = key table of last token
    const int tok_last = srow[L_SEQ - 1];
    float u = K[tok_last * 32 + j];
    float r = 0.f;

    const float cbase  = mem ? 0.f : 1.f;
    const float cscale = mem ? (1.f / (float)L_SEQ) : 0.f;

    // prefetch p = NPOS-1
    int tk = srow[NPOS - 1];
    float kv = K[tk * 32 + j];
    float hv = H[tk * 32 + j];

    for (int p = NPOS - 1; p >= 0; --p) {
        // prefetch next step's k/h (independent of the serial chain)
        const int pn = (p > 0) ? (p - 1) : 0;
        const int tn = srow[pn];
        const float kn = K[tn * 32 + j];
        const float hn = H[tn * 32 + j];

        // d = k . u   (32-lane reduce, all lanes get the sum)
        float d = kv * u;
        #pragma unroll
        for (int m = 1; m <= 16; m <<= 1) d += __shfl_xor(d, m);

        const float c = cbase + cscale * (float)(p + 1);
        const float e = c * d;
        r += e * hv;       // r_p uses u_p (pre-update)
        u -= kv * e;       // u_{p-1}

        kv = kn; hv = hn;
    }

    rbuf[b * 64 + lane] = r;   // [rs (lanes 0-31) | re (lanes 32-63)] == concat order
}

// ---------------- Kernel C: output projection ------------------------------
// grid 256 (one block per batch), block 64
__global__ void out_kernel(const float* __restrict__ rbuf,
                           const float* __restrict__ wrp, const float* __restrict__ brp,
                           const float* __restrict__ wout, const float* __restrict__ bout,
                           float* __restrict__ out) {
    const int b = blockIdx.x;
    const int t = threadIdx.x;
    __shared__ float rsh[64];
    __shared__ float ysh[64];

    rsh[t] = rbuf[b * 64 + t];
    __syncthreads();

    float y = brp[t];
    #pragma unroll 8
    for (int k = 0; k < 64; ++k) y += rsh[k] * wrp[k * 64 + t];
    ysh[t] = y;
    __syncthreads();

    float o = bout[t];
    #pragma unroll 8
    for (int k = 0; k < 64; ++k) o += ysh[k] * wout[k * 64 + t];
    out[b * 64 + t] = o;
}

// ---------------- launch ----------------------------------------------------
extern "C" void kernel_launch(void* const* d_in, const int* in_sizes, int n_in,
                              void* d_out, int out_size, void* d_ws, size_t ws_size,
                              hipStream_t stream) {
    const int*   seq   = (const int*)  d_in[0];
    const float* embed = (const float*)d_in[1];
    const float* w1    = (const float*)d_in[2];
    const float* b1    = (const float*)d_in[3];
    const float* w2    = (const float*)d_in[4];
    const float* b2    = (const float*)d_in[5];
    const float* ln_g  = (const float*)d_in[6];
    const float* ln_b  = (const float*)d_in[7];
    const float* ws    = (const float*)d_in[8];
    const float* bs    = (const float*)d_in[9];
    const float* we    = (const float*)d_in[10];
    const float* be    = (const float*)d_in[11];
    const float* wrp   = (const float*)d_in[12];
    const float* brp   = (const float*)d_in[13];
    const float* wout  = (const float*)d_in[14];
    const float* bout  = (const float*)d_in[15];

    float* tabs = (float*)d_ws;          // 8192 floats (32 KB)
    float* rbuf = tabs + 8192;           // 16384 floats (64 KB)

    build_tables<<<64, 64, 0, stream>>>(embed, w1, b1, w2, b2, ln_g, ln_b,
                                        ws, bs, we, be, tabs);
    scan_kernel<<<256, 64, 0, stream>>>(seq, tabs, rbuf);
    out_kernel<<<256, 64, 0, stream>>>(rbuf, wrp, brp, wout, bout, (float*)d_out);
}

// Round 2
// 181.936 us; speedup vs baseline: 2.1327x; 2.1327x over previous
//
#include <hip/hip_runtime.h>
#include <hip/hip_bf16.h>

// DiffAlphaSplitModel: VOCAB=64, H=64, HALF=32, B=256, L=2048.
//  1) 64 distinct tokens -> per-vocab tables for k (normalized) and h (raw),
//     plus a 64x64 Gram table G[v][w] = k_v . k_w per chain.
//  2) r = M_L q via backward recurrence, CHUNKED (T=32):
//       d_q = g_q - sum_{p>q} c_p G[t_q][t_p] d_p   (triangular solve, readlane-based)
//       u  -= sum c_p d_p k_p ;  r += sum c_p d_p h_p
//     Serial chain = readlane + 2 fma per step (no DS ops on the chain).
//  3) Early exit: ||u||^2 decays geometrically (unit keys); break when dead.
//
// ws layout (floats):
//   [0     ..  4095] compact k [2][64][32]
//   [4096  ..  8191] compact h [2][64][32]
//   [8192  .. 16383] kh2 interleaved [2][64][32][2] = {k,h}
//   [16384 .. 24575] Gram [2][64][64]
//   [24576 .. 40959] rbuf [256][64]

#define L_SEQ 2048
#define NPOS  2047
#define TCH   32
#define NCH   64

// ---------------- Kernel A: per-vocab tables -------------------------------
__global__ void build_tables(const float* __restrict__ embed,
                             const float* __restrict__ w1, const float* __restrict__ b1,
                             const float* __restrict__ w2, const float* __restrict__ b2,
                             const float* __restrict__ ln_g, const float* __restrict__ ln_b,
                             const float* __restrict__ ws, const float* __restrict__ bs,
                             const float* __restrict__ we, const float* __restrict__ be,
                             float* __restrict__ tabs) {
    const int v = blockIdx.x;
    const int t = threadIdx.x;        // 0..63
    __shared__ float sh_h[64];
    __shared__ float sh_a[128];
    __shared__ float sh_x[64];

    sh_h[t] = embed[v * 64 + t];
    __syncthreads();

    float acc0 = b1[t], acc1 = b1[t + 64];
    #pragma unroll 8
    for (int k = 0; k < 64; ++k) {
        const float hv = sh_h[k];
        acc0 += hv * w1[k * 128 + t];
        acc1 += hv * w1[k * 128 + t + 64];
    }
    sh_a[t]      = fmaxf(acc0, 0.f);
    sh_a[t + 64] = fmaxf(acc1, 0.f);
    __syncthreads();

    float x = sh_h[t] + b2[t];
    #pragma unroll 8
    for (int k = 0; k < 128; ++k) x += sh_a[k] * w2[k * 64 + t];

    float mu = x;
    for (int m = 1; m <= 32; m <<= 1) mu += __shfl_xor(mu, m);
    mu *= (1.f / 64.f);
    const float dx = x - mu;
    float var = dx * dx;
    for (int m = 1; m <= 32; m <<= 1) var += __shfl_xor(var, m);
    var *= (1.f / 64.f);
    const float hln = dx * rsqrtf(var + 1e-5f) * ln_g[t] + ln_b[t];
    sh_x[t] = hln;
    __syncthreads();

    const int j   = t & 31;
    const int mem = t >> 5;
    const float* W  = mem ? we : ws;
    const float* Bv = mem ? be : bs;
    float p = Bv[j];
    #pragma unroll 8
    for (int k = 0; k < 64; ++k) p += sh_x[k] * W[k * 32 + j];

    float nn = p * p;
    for (int m = 1; m <= 16; m <<= 1) nn += __shfl_xor(nn, m);
    const float kn = p / fmaxf(sqrtf(nn), 1e-12f);

    tabs[(mem * 64 + v) * 32 + j]        = kn;   // normalized key
    tabs[4096 + (mem * 64 + v) * 32 + j] = p;    // raw projection
    tabs[8192 + ((mem * 64 + v) * 32 + j) * 2]     = kn;  // interleaved {k,h}
    tabs[8192 + ((mem * 64 + v) * 32 + j) * 2 + 1] = p;
}

// ---------------- Kernel A2: Gram tables -----------------------------------
// grid 64 (v), block 128: thread = (m, w). G[m][v][w] = k_v . k_w
__global__ void gram_kernel(const float* __restrict__ tabs, float* __restrict__ gout) {
    const int v  = blockIdx.x;
    const int tt = threadIdx.x;          // 0..127
    const int m  = tt >> 6, w = tt & 63;
    __shared__ float kv[64];             // rows of v for both chains
    if (tt < 64) kv[tt] = tabs[((tt >> 5) * 64 + v) * 32 + (tt & 31)];
    __syncthreads();
    const float* kw  = &tabs[(m * 64 + w) * 32];
    const float* kvm = &kv[m * 32];
    float acc = 0.f;
    #pragma unroll 8
    for (int j = 0; j < 32; ++j) acc += kvm[j] * kw[j];
    gout[m * 4096 + v * 64 + w] = acc;
}

// ---------------- Kernel B: chunked backward scan --------------------------
// grid 256 (batch), block 64. lanes 0-31: s-chain (c=1), 32-63: e-chain.
__global__ void __launch_bounds__(64) scan_kernel(const int* __restrict__ seq,
                                                  const float* __restrict__ tabs,
                                                  float* __restrict__ rbuf) {
    const int b    = blockIdx.x;
    const int lane = threadIdx.x;
    const int q    = lane & 31;
    const int mem  = lane >> 5;

    __shared__ float ktab[2 * 64 * 36];   // rows padded to 36 (bank spread, 16B aligned)
    __shared__ float kh2 [2 * 64 * 64];   // {k,h} float pairs, row stride 64
    __shared__ float gt  [2 * 64 * 65];   // Gram rows padded to 65
    __shared__ int   seq_raw[2052];       // [0] = dummy token for p = -1
    __shared__ float ush[64];
    __shared__ float esh[64];
    int* seq_sh = seq_raw + 1;

    // ---- stage tables ----
    for (int i = lane; i < 1024; i += 64) {            // ktab (padded)
        const int m = i >> 9, r = i & 511, v = r >> 3, jj = i & 7;
        float4 val = ((const float4*)tabs)[i];
        *(float4*)&ktab[(m * 64 + v) * 36 + jj * 4] = val;
    }
    for (int i = lane; i < 2048; i += 64)              // kh2 (straight copy)
        ((float4*)kh2)[i] = ((const float4*)(tabs + 8192))[i];
    for (int i = lane; i < 8192; i += 64) {            // gram (padded)
        const int m = i >> 12, v = (i >> 6) & 63, w = i & 63;
        gt[m * 4160 + v * 65 + w] = tabs[16384 + i];
    }
    if (lane == 0) seq_raw[0] = 0;
    {
        const int4* s4 = (const int4*)(seq + b * L_SEQ);
        for (int i = lane; i < 512; i += 64) {
            int4 vv = s4[i];
            seq_sh[i * 4 + 0] = vv.x; seq_sh[i * 4 + 1] = vv.y;
            seq_sh[i * 4 + 2] = vv.z; seq_sh[i * 4 + 3] = vv.w;
        }
    }
    __syncthreads();

    // ---- init: u = normalized query = key of last token ----
    const int tokL = seq_sh[NPOS];
    float u_reg = ktab[(mem * 64 + tokL) * 36 + q];
    ush[lane] = u_reg;
    float r_reg = 0.f;
    const float invL = 1.0f / (float)L_SEQ;
    __syncthreads();

    for (int ci = 0; ci < NCH; ++ci) {
        const int t = NPOS - TCH * (ci + 1);           // 2015, 1983, ..., -1

        // chunk tokens into registers (t == 3 mod 4 -> int4 aligned incl. t=-1)
        int ta[TCH];
        {
            const int4* tp4 = (const int4*)&seq_sh[t];
            #pragma unroll
            for (int k2 = 0; k2 < 8; ++k2) {
                int4 vv = tp4[k2];
                ta[4*k2+0] = vv.x; ta[4*k2+1] = vv.y;
                ta[4*k2+2] = vv.z; ta[4*k2+3] = vv.w;
            }
        }
        const int tq = seq_sh[t + q];                  // per-lane token (clamped by pad)

        // ---- g = k_q . u, plus ||u||^2 (for early exit) ----
        const float4* krow = (const float4*)&ktab[(mem * 64 + tq) * 36];
        const float4* urow = (const float4*)&ush[mem * 32];
        float g = 0.f, nv = 0.f;
        #pragma unroll
        for (int k2 = 0; k2 < 8; ++k2) {
            float4 kk = krow[k2], uu = urow[k2];
            g  += kk.x*uu.x + kk.y*uu.y + kk.z*uu.z + kk.w*uu.w;
            nv += uu.x*uu.x + uu.y*uu.y + uu.z*uu.z + uu.w*uu.w;
        }
        if (__all(nv < 1e-12f)) break;                 // both chains dead -> tail ~ 0

        // ---- Gram prefetch: a[ps] = mask(q<ps) * c_p * G[tq][tp] ----
        float aS[TCH], aE[TCH];
        const float* grow = &gt[mem * 4160 + tq * 65];
        #pragma unroll
        for (int ps = 1; ps < TCH; ++ps) {
            const float gv2 = grow[ta[ps]];
            const bool  upd = (q < ps);
            const float ce  = (float)(t + ps + 1) * invL;
            aS[ps] = (mem == 0 && upd) ? gv2      : 0.f;
            aE[ps] = (mem == 1 && upd) ? gv2 * ce : 0.f;
        }

        // ---- triangular solve: serial chain = readlane + 2 fma per step ----
        float dv = g;
        #pragma unroll
        for (int ps = TCH - 1; ps >= 1; --ps) {
            const float dS = __int_as_float(__builtin_amdgcn_readlane(__float_as_int(dv), ps));
            const float dE = __int_as_float(__builtin_amdgcn_readlane(__float_as_int(dv), ps + 32));
            dv = fmaf(-aS[ps], dS, dv);
            dv = fmaf(-aE[ps], dE, dv);
        }

        // ---- e = c_q d_q (masked for p<0 in the final chunk) ----
        const int   pq = t + q;
        const float cq = mem ? (float)(pq + 1) * invL : 1.0f;
        const float ev = (pq >= 0) ? cq * dv : 0.f;
        esh[lane] = ev;
        __syncthreads();

        // ---- rank updates: u -= sum e_p k_p ; r += sum e_p h_p ----
        float ea[TCH];
        {
            const float4* e4 = (const float4*)&esh[mem * 32];
            #pragma unroll
            for (int k2 = 0; k2 < 8; ++k2) {
                float4 vv = e4[k2];
                ea[4*k2+0] = vv.x; ea[4*k2+1] = vv.y;
                ea[4*k2+2] = vv.z; ea[4*k2+3] = vv.w;
            }
        }
        float du = 0.f, dr = 0.f;
        #pragma unroll
        for (int ps = 0; ps < TCH; ++ps) {
            const float2 kh = ((const float2*)kh2)[(mem * 64 + ta[ps]) * 32 + q];
            du = fmaf(-ea[ps], kh.x, du);
            dr = fmaf( ea[ps], kh.y, dr);
        }
        u_reg += du; r_reg += dr;
        __syncthreads();
        ush[lane] = u_reg;
        __syncthreads();
    }

    rbuf[b * 64 + lane] = r_reg;      // [rs | re] = concat order
}

// ---------------- Kernel C: output projection ------------------------------
__global__ void out_kernel(const float* __restrict__ rbuf,
                           const float* __restrict__ wrp, const float* __restrict__ brp,
                           const float* __restrict__ wout, const float* __restrict__ bout,
                           float* __restrict__ out) {
    const int b = blockIdx.x;
    const int t = threadIdx.x;
    __shared__ float rsh[64];
    __shared__ float ysh[64];

    rsh[t] = rbuf[b * 64 + t];
    __syncthreads();

    float y = brp[t];
    #pragma unroll 8
    for (int k = 0; k < 64; ++k) y += rsh[k] * wrp[k * 64 + t];
    ysh[t] = y;
    __syncthreads();

    float o = bout[t];
    #pragma unroll 8
    for (int k = 0; k < 64; ++k) o += ysh[k] * wout[k * 64 + t];
    out[b * 64 + t] = o;
}

// ---------------- launch ----------------------------------------------------
extern "C" void kernel_launch(void* const* d_in, const int* in_sizes, int n_in,
                              void* d_out, int out_size, void* d_ws, size_t ws_size,
                              hipStream_t stream) {
    const int*   seq   = (const int*)  d_in[0];
    const float* embed = (const float*)d_in[1];
    const float* w1    = (const float*)d_in[2];
    const float* b1    = (const float*)d_in[3];
    const float* w2    = (const float*)d_in[4];
    const float* b2    = (const float*)d_in[5];
    const float* ln_g  = (const float*)d_in[6];
    const float* ln_b  = (const float*)d_in[7];
    const float* ws    = (const float*)d_in[8];
    const float* bs    = (const float*)d_in[9];
    const float* we    = (const float*)d_in[10];
    const float* be    = (const float*)d_in[11];
    const float* wrp   = (const float*)d_in[12];
    const float* brp   = (const float*)d_in[13];
    const float* wout  = (const float*)d_in[14];
    const float* bout  = (const float*)d_in[15];

    float* tabs = (float*)d_ws;              // 16384 floats (tables)
    float* gout = tabs + 16384;              // 8192 floats (gram)
    float* rbuf = tabs + 24576;              // 16384 floats

    build_tables<<<64, 64, 0, stream>>>(embed, w1, b1, w2, b2, ln_g, ln_b,
                                        ws, bs, we, be, tabs);
    gram_kernel<<<64, 128, 0, stream>>>(tabs, gout);
    scan_kernel<<<256, 64, 0, stream>>>(seq, tabs, rbuf);
    out_kernel<<<256, 64, 0, stream>>>(rbuf, wrp, brp, wout, bout, (float*)d_out);
}

// Round 3
// 115.375 us; speedup vs baseline: 3.3631x; 1.5769x over previous
//
#include <hip/hip_runtime.h>
#include <hip/hip_bf16.h>

// DiffAlphaSplitModel: VOCAB=64, H=64, HALF=32, B=256, L=2048.
//  1) 64 distinct tokens -> per-vocab tables: k (normalized), h (raw),
//     Gram G[v][w] = k_v . k_w per chain.
//  2) r = M_L q via backward recurrence, CHUNKED (T=32):
//       d_q = g_q - sum_{ps>q} c_ps G[t_q][t_ps] d_ps   (triangular solve)
//       u  -= sum c_p d_p k_p ;  r += sum c_p d_p h_p
//  3) This version: s-chain and e-chain in SEPARATE WAVES (block=128).
//     u kept in registers; all cross-lane traffic via v_readlane.
//     No barriers and no LDS writes inside the chunk loop.
//
// ws layout (floats):
//   [0     ..  4095] compact k [2][64][32]
//   [4096  ..  8191] compact h [2][64][32]
//   [8192  .. 16383] kh2 interleaved [2][64][32][2] = {k,h}
//   [16384 .. 24575] Gram [2][64][64]
//   [24576 .. 40959] rbuf [256][64]

#define L_SEQ 2048
#define NPOS  2047
#define TCH   32
#define NCH   64

__device__ __forceinline__ float rdlane(float v, int l) {
    return __int_as_float(__builtin_amdgcn_readlane(__float_as_int(v), l));
}

// ---------------- Kernel A: per-vocab tables -------------------------------
__global__ void build_tables(const float* __restrict__ embed,
                             const float* __restrict__ w1, const float* __restrict__ b1,
                             const float* __restrict__ w2, const float* __restrict__ b2,
                             const float* __restrict__ ln_g, const float* __restrict__ ln_b,
                             const float* __restrict__ ws, const float* __restrict__ bs,
                             const float* __restrict__ we, const float* __restrict__ be,
                             float* __restrict__ tabs) {
    const int v = blockIdx.x;
    const int t = threadIdx.x;        // 0..63
    __shared__ float sh_h[64];
    __shared__ float sh_a[128];
    __shared__ float sh_x[64];

    sh_h[t] = embed[v * 64 + t];
    __syncthreads();

    float acc0 = b1[t], acc1 = b1[t + 64];
    #pragma unroll 8
    for (int k = 0; k < 64; ++k) {
        const float hv = sh_h[k];
        acc0 += hv * w1[k * 128 + t];
        acc1 += hv * w1[k * 128 + t + 64];
    }
    sh_a[t]      = fmaxf(acc0, 0.f);
    sh_a[t + 64] = fmaxf(acc1, 0.f);
    __syncthreads();

    float x = sh_h[t] + b2[t];
    #pragma unroll 8
    for (int k = 0; k < 128; ++k) x += sh_a[k] * w2[k * 64 + t];

    float mu = x;
    for (int m = 1; m <= 32; m <<= 1) mu += __shfl_xor(mu, m);
    mu *= (1.f / 64.f);
    const float dx = x - mu;
    float var = dx * dx;
    for (int m = 1; m <= 32; m <<= 1) var += __shfl_xor(var, m);
    var *= (1.f / 64.f);
    const float hln = dx * rsqrtf(var + 1e-5f) * ln_g[t] + ln_b[t];
    sh_x[t] = hln;
    __syncthreads();

    const int j   = t & 31;
    const int mem = t >> 5;
    const float* W  = mem ? we : ws;
    const float* Bv = mem ? be : bs;
    float p = Bv[j];
    #pragma unroll 8
    for (int k = 0; k < 64; ++k) p += sh_x[k] * W[k * 32 + j];

    float nn = p * p;
    for (int m = 1; m <= 16; m <<= 1) nn += __shfl_xor(nn, m);
    const float kn = p / fmaxf(sqrtf(nn), 1e-12f);

    tabs[(mem * 64 + v) * 32 + j]        = kn;   // normalized key
    tabs[4096 + (mem * 64 + v) * 32 + j] = p;    // raw projection
    tabs[8192 + ((mem * 64 + v) * 32 + j) * 2]     = kn;  // interleaved {k,h}
    tabs[8192 + ((mem * 64 + v) * 32 + j) * 2 + 1] = p;
}

// ---------------- Kernel A2: Gram tables -----------------------------------
__global__ void gram_kernel(const float* __restrict__ tabs, float* __restrict__ gout) {
    const int v  = blockIdx.x;
    const int tt = threadIdx.x;          // 0..127
    const int m  = tt >> 6, w = tt & 63;
    __shared__ float kv[64];
    if (tt < 64) kv[tt] = tabs[((tt >> 5) * 64 + v) * 32 + (tt & 31)];
    __syncthreads();
    const float* kw  = &tabs[(m * 64 + w) * 32];
    const float* kvm = &kv[m * 32];
    float acc = 0.f;
    #pragma unroll 8
    for (int j = 0; j < 32; ++j) acc += kvm[j] * kw[j];
    gout[m * 4096 + v * 64 + w] = acc;
}

// ---------------- Kernel B: chunked backward scan --------------------------
// grid 256 (batch), block 128 = 2 waves. wave 0: s-chain (c=1), wave 1: e-chain.
// Lanes 32-63 of each wave duplicate lanes 0-31 (latency-bound; harmless).
__global__ void __launch_bounds__(128, 1) scan_kernel(const int* __restrict__ seq,
                                                      const float* __restrict__ tabs,
                                                      float* __restrict__ rbuf) {
    const int b    = blockIdx.x;
    const int tid  = threadIdx.x;        // 0..127
    const int mem  = tid >> 6;           // wave id == chain id
    const int lane = tid & 63;
    const int q    = lane & 31;

    __shared__ float ktab[2 * 64 * 36];   // rows padded to 36 floats (16B-aligned)
    __shared__ float kh2 [2 * 64 * 64];   // {k,h} float pairs, row stride 64
    __shared__ float gt  [2 * 64 * 65];   // Gram rows padded to 65
    __shared__ int   seq_raw[2052];       // [0] = dummy token for p = -1
    int* seq_sh = seq_raw + 1;

    // ---- stage tables (one-time; single barrier) ----
    for (int i = tid; i < 1024; i += 128) {
        const int m = i >> 9, v = (i & 511) >> 3, jj = i & 7;
        float4 val = ((const float4*)tabs)[i];
        *(float4*)&ktab[(m * 64 + v) * 36 + jj * 4] = val;
    }
    for (int i = tid; i < 2048; i += 128)
        ((float4*)kh2)[i] = ((const float4*)(tabs + 8192))[i];
    for (int i = tid; i < 8192; i += 128) {
        const int m = i >> 12, v = (i >> 6) & 63, w = i & 63;
        gt[m * 4160 + v * 65 + w] = tabs[16384 + i];
    }
    if (tid == 0) seq_raw[0] = 0;
    {
        const int4* s4 = (const int4*)(seq + b * L_SEQ);
        for (int i = tid; i < 512; i += 128) {
            int4 vv = s4[i];
            seq_sh[i * 4 + 0] = vv.x; seq_sh[i * 4 + 1] = vv.y;
            seq_sh[i * 4 + 2] = vv.z; seq_sh[i * 4 + 3] = vv.w;
        }
    }
    __syncthreads();

    // ---- init: u = normalized query = key of last token (lane q holds u_q) ----
    const int tokL = seq_sh[NPOS];
    float u_reg = ktab[(mem * 64 + tokL) * 36 + q];
    float r_reg = 0.f;
    const float invL = 1.0f / (float)L_SEQ;

    for (int ci = 0; ci < NCH; ++ci) {
        const int t = NPOS - TCH * (ci + 1);           // 2015, 1983, ..., -1

        // chunk tokens -> registers (16B aligned: t == 3 mod 4, seq_sh off-by-1 pad)
        int ta[TCH];
        {
            const int4* tp4 = (const int4*)&seq_sh[t];
            #pragma unroll
            for (int k2 = 0; k2 < 8; ++k2) {
                int4 vv = tp4[k2];
                ta[4*k2+0] = vv.x; ta[4*k2+1] = vv.y;
                ta[4*k2+2] = vv.z; ta[4*k2+3] = vv.w;
            }
        }
        const int tq = seq_sh[t + q];                  // per-lane token

        // ---- prefetch all LDS operands for this chunk (independent of u) ----
        float4 kr[8];                                  // k row of tq
        {
            const float4* krow = (const float4*)&ktab[(mem * 64 + tq) * 36];
            #pragma unroll
            for (int k2 = 0; k2 < 8; ++k2) kr[k2] = krow[k2];
        }
        float2 kh[TCH];                                // {k,h} pairs, lane component q
        #pragma unroll
        for (int ps = 0; ps < TCH; ++ps)
            kh[ps] = ((const float2*)kh2)[(mem * 64 + ta[ps]) * 32 + q];

        float aW[TCH];                                 // masked solve coefficients
        {
            const float* grow = &gt[mem * 4160 + tq * 65];
            #pragma unroll
            for (int ps = 1; ps < TCH; ++ps) {
                const float gv = grow[ta[ps]];
                const float cf = mem ? (float)(t + ps + 1) * invL : 1.0f;
                aW[ps] = (q < ps) ? cf * gv : 0.f;
            }
        }

        // ---- g = k_tq . u  and  ||u||^2, via readlane broadcast (no LDS) ----
        float ga0=0.f, ga1=0.f, ga2=0.f, ga3=0.f;
        float na0=0.f, na1=0.f;
        const float* krf = (const float*)kr;
        #pragma unroll
        for (int j = 0; j < 32; j += 4) {
            const float u0 = rdlane(u_reg, j+0), u1 = rdlane(u_reg, j+1);
            const float u2 = rdlane(u_reg, j+2), u3 = rdlane(u_reg, j+3);
            ga0 = fmaf(krf[j+0], u0, ga0);  ga1 = fmaf(krf[j+1], u1, ga1);
            ga2 = fmaf(krf[j+2], u2, ga2);  ga3 = fmaf(krf[j+3], u3, ga3);
            na0 = fmaf(u0, u0, na0);        na1 = fmaf(u1, u1, na1);
            na0 = fmaf(u2, u2, na0);        na1 = fmaf(u3, u3, na1);
        }
        const float g  = (ga0 + ga1) + (ga2 + ga3);
        const float nv = na0 + na1;                    // wave-uniform
        if (nv < 1e-12f) break;                        // this chain is dead

        // ---- triangular solve: chain = readlane + fma per step ----
        float dv = g;
        #pragma unroll
        for (int ps = TCH - 1; ps >= 1; --ps) {
            const float ds = rdlane(dv, ps);
            dv = fmaf(-aW[ps], ds, dv);
        }

        // ---- e = c_q d_q (masked for p<0 in the final chunk) ----
        const int   pq = t + q;
        const float cq = mem ? (float)(pq + 1) * invL : 1.0f;
        const float ev = (pq >= 0) ? cq * dv : 0.f;

        // ---- rank updates via readlane broadcast of e ----
        float du0=0.f, du1=0.f, dr0=0.f, dr1=0.f;
        #pragma unroll
        for (int ps = 0; ps < TCH; ps += 2) {
            const float e0 = rdlane(ev, ps);
            const float e1 = rdlane(ev, ps + 1);
            du0 = fmaf(-e0, kh[ps].x,   du0);
            dr0 = fmaf( e0, kh[ps].y,   dr0);
            du1 = fmaf(-e1, kh[ps+1].x, du1);
            dr1 = fmaf( e1, kh[ps+1].y, dr1);
        }
        u_reg += du0 + du1;
        r_reg += dr0 + dr1;
    }

    if (lane < 32)
        rbuf[b * 64 + mem * 32 + q] = r_reg;   // [rs | re] = concat order
}

// ---------------- Kernel C: output projection ------------------------------
__global__ void out_kernel(const float* __restrict__ rbuf,
                           const float* __restrict__ wrp, const float* __restrict__ brp,
                           const float* __restrict__ wout, const float* __restrict__ bout,
                           float* __restrict__ out) {
    const int b = blockIdx.x;
    const int t = threadIdx.x;
    __shared__ float rsh[64];
    __shared__ float ysh[64];

    rsh[t] = rbuf[b * 64 + t];
    __syncthreads();

    float y = brp[t];
    #pragma unroll 8
    for (int k = 0; k < 64; ++k) y += rsh[k] * wrp[k * 64 + t];
    ysh[t] = y;
    __syncthreads();

    float o = bout[t];
    #pragma unroll 8
    for (int k = 0; k < 64; ++k) o += ysh[k] * wout[k * 64 + t];
    out[b * 64 + t] = o;
}

// ---------------- launch ----------------------------------------------------
extern "C" void kernel_launch(void* const* d_in, const int* in_sizes, int n_in,
                              void* d_out, int out_size, void* d_ws, size_t ws_size,
                              hipStream_t stream) {
    const int*   seq   = (const int*)  d_in[0];
    const float* embed = (const float*)d_in[1];
    const float* w1    = (const float*)d_in[2];
    const float* b1    = (const float*)d_in[3];
    const float* w2    = (const float*)d_in[4];
    const float* b2    = (const float*)d_in[5];
    const float* ln_g  = (const float*)d_in[6];
    const float* ln_b  = (const float*)d_in[7];
    const float* ws    = (const float*)d_in[8];
    const float* bs    = (const float*)d_in[9];
    const float* we    = (const float*)d_in[10];
    const float* be    = (const float*)d_in[11];
    const float* wrp   = (const float*)d_in[12];
    const float* brp   = (const float*)d_in[13];
    const float* wout  = (const float*)d_in[14];
    const float* bout  = (const float*)d_in[15];

    float* tabs = (float*)d_ws;              // 16384 floats
    float* gout = tabs + 16384;              // 8192 floats
    float* rbuf = tabs + 24576;              // 16384 floats

    build_tables<<<64, 64, 0, stream>>>(embed, w1, b1, w2, b2, ln_g, ln_b,
                                        ws, bs, we, be, tabs);
    gram_kernel<<<64, 128, 0, stream>>>(tabs, gout);
    scan_kernel<<<256, 128, 0, stream>>>(seq, tabs, rbuf);
    out_kernel<<<256, 64, 0, stream>>>(rbuf, wrp, brp, wout, bout, (float*)d_out);
}

// Round 5
// 108.455 us; speedup vs baseline: 3.5776x; 1.0638x over previous
//
#include <hip/hip_runtime.h>
#include <hip/hip_bf16.h>

// DiffAlphaSplitModel: VOCAB=64, H=64, HALF=32, B=256, L=2048.
//  1) 64 distinct tokens -> per-vocab tables: k (normalized), h (raw),
//     Gram G[v][w] = k_v . k_w per chain.
//  2) r = M_L q via backward recurrence, CHUNKED (T=32):
//       d_q = g_q - sum_{ps>q} c_ps G[t_q][t_ps] d_ps   (triangular solve)
//  3) DUAL-SPACE state: instead of u (32-dim), keep gf_v = k_v . u for all
//     64 vocab (lane = v). Rank-1 updates of u become
//       gf_v -= sum_q e_q G[v][ta_q]     (G column reads: row = lane -> conflict-free)
//       r_j  += sum_q e_q h[ta_q][j]     (h column reads: bank = lane -> conflict-free)
//     No k-row gathers, no kh table, no u->g matvec. Early exit when all
//     |gf| tiny (sound: 64 keys span R^32, and (I - c k k^T) is non-expansive).
//  s-chain and e-chain in separate waves (block=128). No barriers/LDS writes
//  in the main loop.
//
//  ROUND-5 FIX: hsh staging copied only 2048 of 4096 floats (e-chain h table
//  was uninitialized LDS -> re garbage, absmax 3.26). Now copies 1024 float4.
//
// ws layout (floats):
//   [0     ..  4095] compact k [2][64][32]
//   [4096  ..  8191] compact h [2][64][32]
//   [16384 .. 24575] Gram [2][64][64]
//   [24576 .. 40959] rbuf [256][64]

#define L_SEQ 2048
#define NPOS  2047
#define TCH   32
#define NCH   64

__device__ __forceinline__ float rdlane(float v, int l) {
    return __int_as_float(__builtin_amdgcn_readlane(__float_as_int(v), l));
}

// ---------------- Kernel A: per-vocab tables -------------------------------
__global__ void build_tables(const float* __restrict__ embed,
                             const float* __restrict__ w1, const float* __restrict__ b1,
                             const float* __restrict__ w2, const float* __restrict__ b2,
                             const float* __restrict__ ln_g, const float* __restrict__ ln_b,
                             const float* __restrict__ ws, const float* __restrict__ bs,
                             const float* __restrict__ we, const float* __restrict__ be,
                             float* __restrict__ tabs) {
    const int v = blockIdx.x;
    const int t = threadIdx.x;        // 0..63
    __shared__ float sh_h[64];
    __shared__ float sh_a[128];
    __shared__ float sh_x[64];

    sh_h[t] = embed[v * 64 + t];
    __syncthreads();

    float acc0 = b1[t], acc1 = b1[t + 64];
    #pragma unroll 8
    for (int k = 0; k < 64; ++k) {
        const float hv = sh_h[k];
        acc0 += hv * w1[k * 128 + t];
        acc1 += hv * w1[k * 128 + t + 64];
    }
    sh_a[t]      = fmaxf(acc0, 0.f);
    sh_a[t + 64] = fmaxf(acc1, 0.f);
    __syncthreads();

    float x = sh_h[t] + b2[t];
    #pragma unroll 8
    for (int k = 0; k < 128; ++k) x += sh_a[k] * w2[k * 64 + t];

    float mu = x;
    for (int m = 1; m <= 32; m <<= 1) mu += __shfl_xor(mu, m);
    mu *= (1.f / 64.f);
    const float dx = x - mu;
    float var = dx * dx;
    for (int m = 1; m <= 32; m <<= 1) var += __shfl_xor(var, m);
    var *= (1.f / 64.f);
    const float hln = dx * rsqrtf(var + 1e-5f) * ln_g[t] + ln_b[t];
    sh_x[t] = hln;
    __syncthreads();

    const int j   = t & 31;
    const int mem = t >> 5;
    const float* W  = mem ? we : ws;
    const float* Bv = mem ? be : bs;
    float p = Bv[j];
    #pragma unroll 8
    for (int k = 0; k < 64; ++k) p += sh_x[k] * W[k * 32 + j];

    float nn = p * p;
    for (int m = 1; m <= 16; m <<= 1) nn += __shfl_xor(nn, m);
    const float kn = p / fmaxf(sqrtf(nn), 1e-12f);

    tabs[(mem * 64 + v) * 32 + j]        = kn;   // normalized key
    tabs[4096 + (mem * 64 + v) * 32 + j] = p;    // raw projection
}

// ---------------- Kernel A2: Gram tables -----------------------------------
__global__ void gram_kernel(const float* __restrict__ tabs, float* __restrict__ gout) {
    const int v  = blockIdx.x;
    const int tt = threadIdx.x;          // 0..127
    const int m  = tt >> 6, w = tt & 63;
    __shared__ float kv[64];
    if (tt < 64) kv[tt] = tabs[((tt >> 5) * 64 + v) * 32 + (tt & 31)];
    __syncthreads();
    const float* kw  = &tabs[(m * 64 + w) * 32];
    const float* kvm = &kv[m * 32];
    float acc = 0.f;
    #pragma unroll 8
    for (int j = 0; j < 32; ++j) acc += kvm[j] * kw[j];
    gout[m * 4096 + v * 64 + w] = acc;
}

// ---------------- Kernel B: chunked backward scan (dual-space) -------------
// grid 256 (batch), block 128 = 2 waves. wave 0: s-chain (c=1), wave 1: e-chain.
// lane (0..63) = vocab id v for gf;  q = lane&31 = chunk position for solve.
__global__ void __launch_bounds__(128, 1) scan_kernel(const int* __restrict__ seq,
                                                      const float* __restrict__ tabs,
                                                      float* __restrict__ rbuf) {
    const int b    = blockIdx.x;
    const int tid  = threadIdx.x;        // 0..127
    const int m    = tid >> 6;           // wave id == chain id
    const int lane = tid & 63;           // vocab id v
    const int q    = lane & 31;          // chunk position

    __shared__ float gt [2 * 64 * 65];   // Gram rows padded to 65
    __shared__ float hsh[2 * 64 * 32];   // h tables [m][v][j]
    __shared__ int   seq_raw[2052];      // [0] = dummy token for p = -1
    int* seq_sh = seq_raw + 1;

    // ---- stage (one-time) ----
    for (int i = tid; i < 8192; i += 128) {
        const int mm = i >> 12, v = (i >> 6) & 63, w = i & 63;
        gt[mm * 4160 + v * 65 + w] = tabs[16384 + i];
    }
    for (int i = tid; i < 1024; i += 128)              // FIX: 1024 float4 = 4096 floats
        ((float4*)hsh)[i] = ((const float4*)(tabs + 4096))[i];
    if (tid == 0) seq_raw[0] = 0;
    {
        const int4* s4 = (const int4*)(seq + b * L_SEQ);
        for (int i = tid; i < 512; i += 128) {
            int4 vv = s4[i];
            seq_sh[i * 4 + 0] = vv.x; seq_sh[i * 4 + 1] = vv.y;
            seq_sh[i * 4 + 2] = vv.z; seq_sh[i * 4 + 3] = vv.w;
        }
    }
    __syncthreads();

    // ---- init: u = k_tokL  =>  gf_v = G[v][tokL] ----
    const int tokL = seq_sh[NPOS];
    float gf   = gt[m * 4160 + lane * 65 + tokL];
    float racc = 0.f;
    const float invL = 1.0f / (float)L_SEQ;

    for (int ci = 0; ci < NCH; ++ci) {
        if (__all(fabsf(gf) < 1e-6f)) break;       // residual-based exit (per wave)

        const int t = NPOS - TCH * (ci + 1);       // 2015, 1983, ..., -1

        // chunk tokens -> registers (16B aligned: t == 3 mod 4, +1 pad)
        int ta[TCH];
        {
            const int4* tp4 = (const int4*)&seq_sh[t];
            #pragma unroll
            for (int k2 = 0; k2 < 8; ++k2) {
                int4 vv = tp4[k2];
                ta[4*k2+0] = vv.x; ta[4*k2+1] = vv.y;
                ta[4*k2+2] = vv.z; ta[4*k2+3] = vv.w;
            }
        }
        const int tq = seq_sh[t + q];              // per-lane token at position q

        // ---- solve coefficients: aW[ps] = mask(q<ps) * c_ps * G[tq][ta_ps] ----
        float aW[TCH];
        {
            const float* growq = &gt[m * 4160 + tq * 65];
            #pragma unroll
            for (int ps = 1; ps < TCH; ++ps) {
                const float gv = growq[ta[ps]];
                const float cf = m ? (float)(t + ps + 1) * invL : 1.0f;
                aW[ps] = (q < ps) ? cf * gv : 0.f;
            }
        }

        // ---- state-update operands (row = lane -> 2-way/conflict-free) ----
        float Gc[TCH], Hc[TCH];
        {
            const float* growv = &gt[m * 4160 + lane * 65];
            #pragma unroll
            for (int qq = 0; qq < TCH; ++qq) {
                Gc[qq] = growv[ta[qq]];                       // G[v][ta_qq]
                Hc[qq] = hsh[(m * 64 + ta[qq]) * 32 + q];     // h[ta_qq][q]
            }
        }

        // ---- g into position space: g_q = gf[tq] ----
        const float gq = __int_as_float(
            __builtin_amdgcn_ds_bpermute(tq << 2, __float_as_int(gf)));

        // ---- triangular solve: chain = readlane + fma per step ----
        float dv = gq;
        #pragma unroll
        for (int ps = TCH - 1; ps >= 1; --ps)
            dv = fmaf(-aW[ps], rdlane(dv, ps), dv);

        // ---- e = c_q d_q (masked for p<0 in final chunk) ----
        const int   pq = t + q;
        const float cq = m ? (float)(pq + 1) * invL : 1.0f;
        const float ev = (pq >= 0) ? cq * dv : 0.f;

        // ---- state updates: gf -= sum e G-col ; r += sum e h-col ----
        float gA=0.f, gB=0.f, rA=0.f, rB=0.f;
        #pragma unroll
        for (int qq = 0; qq < TCH; qq += 2) {
            const float e0 = rdlane(ev, qq);
            const float e1 = rdlane(ev, qq + 1);
            gA = fmaf(e0, Gc[qq],   gA);  rA = fmaf(e0, Hc[qq],   rA);
            gB = fmaf(e1, Gc[qq+1], gB);  rB = fmaf(e1, Hc[qq+1], rB);
        }
        gf   -= gA + gB;
        racc += rA + rB;
    }

    if (lane < 32)
        rbuf[b * 64 + m * 32 + q] = racc;   // [rs | re] = concat order
}

// ---------------- Kernel C: output projection ------------------------------
__global__ void out_kernel(const float* __restrict__ rbuf,
                           const float* __restrict__ wrp, const float* __restrict__ brp,
                           const float* __restrict__ wout, const float* __restrict__ bout,
                           float* __restrict__ out) {
    const int b = blockIdx.x;
    const int t = threadIdx.x;
    __shared__ float rsh[64];
    __shared__ float ysh[64];

    rsh[t] = rbuf[b * 64 + t];
    __syncthreads();

    float y = brp[t];
    #pragma unroll 8
    for (int k = 0; k < 64; ++k) y += rsh[k] * wrp[k * 64 + t];
    ysh[t] = y;
    __syncthreads();

    float o = bout[t];
    #pragma unroll 8
    for (int k = 0; k < 64; ++k) o += ysh[k] * wout[k * 64 + t];
    out[b * 64 + t] = o;
}

// ---------------- launch ----------------------------------------------------
extern "C" void kernel_launch(void* const* d_in, const int* in_sizes, int n_in,
                              void* d_out, int out_size, void* d_ws, size_t ws_size,
                              hipStream_t stream) {
    const int*   seq   = (const int*)  d_in[0];
    const float* embed = (const float*)d_in[1];
    const float* w1    = (const float*)d_in[2];
    const float* b1    = (const float*)d_in[3];
    const float* w2    = (const float*)d_in[4];
    const float* b2    = (const float*)d_in[5];
    const float* ln_g  = (const float*)d_in[6];
    const float* ln_b  = (const float*)d_in[7];
    const float* ws    = (const float*)d_in[8];
    const float* bs    = (const float*)d_in[9];
    const float* we    = (const float*)d_in[10];
    const float* be    = (const float*)d_in[11];
    const float* wrp   = (const float*)d_in[12];
    const float* brp   = (const float*)d_in[13];
    const float* wout  = (const float*)d_in[14];
    const float* bout  = (const float*)d_in[15];

    float* tabs = (float*)d_ws;              // tables + gram
    float* gout = tabs + 16384;              // gram [2][64][64]
    float* rbuf = tabs + 24576;              // r vectors [256][64]

    build_tables<<<64, 64, 0, stream>>>(embed, w1, b1, w2, b2, ln_g, ln_b,
                                        ws, bs, we, be, tabs);
    gram_kernel<<<64, 128, 0, stream>>>(tabs, gout);
    scan_kernel<<<256, 128, 0, stream>>>(seq, tabs, rbuf);
    out_kernel<<<256, 64, 0, stream>>>(rbuf, wrp, brp, wout, bout, (float*)d_out);
}